// Round 2
// baseline (21.051 us; speedup 1.0000x reference)
//
#include <hip/hip_runtime.h>

#define THREADS 256

// Closed-form 4-point homography (projective basis method).
// Matches reference: solve A h = b (8x8 DLT), H = [h; 1] row-major, H[2][2]=1.
__global__ __launch_bounds__(THREADS) void dlt_kernel(
    const float4* __restrict__ cA,   // corners_A as float4 pairs: [B][2]
    const float4* __restrict__ dl,   // delta as float4 pairs:     [B][2]
    float* __restrict__ out,         // [B][9] row-major H
    int B)
{
    __shared__ float lds[THREADS * 9];
    const int tid = threadIdx.x;
    const int b = blockIdx.x * THREADS + tid;

    float h[9];
    #pragma unroll
    for (int k = 0; k < 9; ++k) h[k] = 0.0f;

    if (b < B) {
        const float4 c0 = cA[2 * b + 0];
        const float4 c1 = cA[2 * b + 1];
        const float4 e0 = dl[2 * b + 0];
        const float4 e1 = dl[2 * b + 1];

        // source corners
        const float u1 = c0.x, v1 = c0.y, u2 = c0.z, v2 = c0.w;
        const float u3 = c1.x, v3 = c1.y, u4 = c1.z, v4 = c1.w;
        // target corners = source + delta
        const float p1 = u1 + e0.x, q1 = v1 + e0.y;
        const float p2 = u2 + e0.z, q2 = v2 + e0.w;
        const float p3 = u3 + e1.x, q3 = v3 + e1.y;
        const float p4 = u4 + e1.z, q4 = v4 + e1.w;

        // det of columns [(ax,ay,1),(bx,by,1),(cx,cy,1)] via difference form
        #define DET3(ax,ay,bx,by,cx,cy) \
            (((bx) - (ax)) * ((cy) - (ay)) - ((cx) - (ax)) * ((by) - (ay)))

        // Cramer dets: column i of [a1 a2 a3] replaced by a4
        const float D1a = DET3(u4, v4, u2, v2, u3, v3);
        const float D2a = DET3(u1, v1, u4, v4, u3, v3);
        const float D3a = DET3(u1, v1, u2, v2, u4, v4);
        const float D1b = DET3(p4, q4, p2, q2, p3, q3);
        const float D2b = DET3(p1, q1, p4, q4, p3, q3);
        const float D3b = DET3(p1, q1, p2, q2, p4, q4);

        // coefficients c_i = D_i^b * prod_{j!=i} D_j^a (common scale dropped)
        const float k1 = D1b * (D2a * D3a);
        const float k2 = D2b * (D3a * D1a);
        const float k3 = D3b * (D1a * D2a);

        // g_i = a_j x a_k (cyclic), a=(u,v,1)
        const float g1x = v2 - v3, g1y = u3 - u2, g1z = u2 * v3 - u3 * v2;
        const float g2x = v3 - v1, g2y = u1 - u3, g2z = u3 * v1 - u1 * v3;
        const float g3x = v1 - v2, g3y = u2 - u1, g3z = u1 * v2 - u2 * v1;

        // H = sum_i k_i * outer((p_i,q_i,1), g_i)
        const float w1 = k1 * p1, w2 = k2 * p2, w3 = k3 * p3;
        const float x1 = k1 * q1, x2 = k2 * q2, x3 = k3 * q3;

        const float H00 = w1 * g1x + w2 * g2x + w3 * g3x;
        const float H01 = w1 * g1y + w2 * g2y + w3 * g3y;
        const float H02 = w1 * g1z + w2 * g2z + w3 * g3z;
        const float H10 = x1 * g1x + x2 * g2x + x3 * g3x;
        const float H11 = x1 * g1y + x2 * g2y + x3 * g3y;
        const float H12 = x1 * g1z + x2 * g2z + x3 * g3z;
        const float H20 = k1 * g1x + k2 * g2x + k3 * g3x;
        const float H21 = k1 * g1y + k2 * g2y + k3 * g3y;
        const float H22 = k1 * g1z + k2 * g2z + k3 * g3z;

        const float r = 1.0f / H22;
        h[0] = H00 * r; h[1] = H01 * r; h[2] = H02 * r;
        h[3] = H10 * r; h[4] = H11 * r; h[5] = H12 * r;
        h[6] = H20 * r; h[7] = H21 * r; h[8] = 1.0f;
    }

    // LDS transpose: [tid][k] -> contiguous block of THREADS*9 floats,
    // then fully coalesced stride-1 global stores.
    #pragma unroll
    for (int k = 0; k < 9; ++k) lds[tid * 9 + k] = h[k];
    __syncthreads();

    const long long base = (long long)blockIdx.x * (THREADS * 9);
    const long long total = (long long)B * 9;
    #pragma unroll
    for (int k = 0; k < 9; ++k) {
        const int i = k * THREADS + tid;
        const long long gi = base + i;
        if (gi < total) out[gi] = lds[i];
    }
}

extern "C" void kernel_launch(void* const* d_in, const int* in_sizes, int n_in,
                              void* d_out, int out_size, void* d_ws, size_t ws_size,
                              hipStream_t stream) {
    const int B = in_sizes[0] / 8;  // corners_A: [B,4,2] floats
    const float4* cA = (const float4*)d_in[0];
    const float4* dl = (const float4*)d_in[1];
    float* out = (float*)d_out;
    const int grid = (B + THREADS - 1) / THREADS;
    dlt_kernel<<<grid, THREADS, 0, stream>>>(cA, dl, out, B);
}